// Round 10
// baseline (48.779 us; speedup 1.0000x reference)
//
#include <hip/hip_runtime.h>

#define B_Q   8
#define DB    128
#define R_REF 4096
#define S_EDGE 32768
#define NSEG  1024
#define DBITS 1024
#define OUTD  512

#define NB_GEMM 512
#define NB_DIST 2048
#define NB_BOUNDS 4
#define TILE_E 256

typedef __bf16 bf16_t;
typedef bf16_t bf16x8 __attribute__((ext_vector_type(8)));
typedef float  f32x4  __attribute__((ext_vector_type(4)));
typedef unsigned int u32;

__device__ inline unsigned short f2bf(float f){
  unsigned int u = __builtin_bit_cast(unsigned int, f);
  u = (u + 0x7fffu + ((u >> 16) & 1u)) >> 16;
  return (unsigned short)u;
}

// Fused front: [0,512) GEMM (self-staged B from W, A unpacked from refs)
//              [512,2560) dists (4 pairs per wave) | [2560,2564) bounds
__global__ __launch_bounds__(256) void k_front(const float* __restrict__ W,
                                               const int* __restrict__ refs,
                                               const int* __restrict__ Q,
                                               const int* __restrict__ Qok,
                                               const int* __restrict__ okpos,
                                               float* __restrict__ distsT,
                                               const int* __restrict__ segments,
                                               int* __restrict__ segstart,
                                               unsigned short* __restrict__ U){
  __shared__ unsigned short AS[2 * 8192];   // 32 KB  [buf][row 64][k 128] swizzled chunks
  __shared__ unsigned short BS[2 * 8192];   // 32 KB
  const int bid = blockIdx.x;
  const int tid = threadIdx.x;

  if (bid < NB_GEMM){
    // ---------------- GEMM role: U[4096][512] bf16 = unpackbits(refs) @ W ----------------
    // XCD-affine: XCD x (bid%8) owns output column group x -> its W slice stays in x's L2.
    const int tn = (bid & 7) * 64, tm = (bid >> 3) * 64;
    const int w = tid >> 6, l = tid & 63;
    const int wm = (w & 1) * 32, wn = (w >> 1) * 32;
    const int lr = l & 15, kq = l >> 4;

    f32x4 acc[2][2] = {};
    int cur = 0;

    // A: thread covers row=tid>>2, global chunks j0..j0+3 (1 byte = 8 bits = 1 chunk),
    // unpack to bf16, write to LDS slot (j0+j)^(row&15)  [R9-proven]
    #define STAGE_A(buf, K0)                                                               \
      do {                                                                                 \
        int row = tid >> 2, j0 = (tid & 3) * 4;                                            \
        int4 rv = *(const int4*)(refs + (size_t)(tm + row) * DB + (K0)/8 + j0);            \
        const int rx = row & 15;                                                           \
        int vv[4] = {rv.x, rv.y, rv.z, rv.w};                                              \
        _Pragma("unroll")                                                                  \
        for (int j = 0; j < 4; ++j){                                                       \
          u32 v = (u32)vv[j];                                                              \
          uint4 o;                                                                         \
          u32* wp = (u32*)&o;                                                              \
          _Pragma("unroll")                                                                \
          for (int i2 = 0; i2 < 4; ++i2){                                                  \
            u32 b0 = (v >> (7 - 2*i2)) & 1u;                                               \
            u32 b1 = (v >> (6 - 2*i2)) & 1u;                                               \
            wp[i2] = b0 * 0x3F80u | ((b1 * 0x3F80u) << 16);                                \
          }                                                                                \
          int lch = (j0 + j) ^ rx;                                                         \
          *(uint4*)(AS + (buf)*8192 + row*128 + lch*8) = o;                                \
        }                                                                                  \
      } while (0)

    // B: transpose-stage from W. idx -> (kpair, oquad); coalesced float4 pair-loads;
    // pack bf16(k),bf16(k+1) -> one b32 at swizzled slot ch = (krel>>3) ^ (row&15).
    #define STAGE_BW(buf, K0)                                                              \
      do {                                                                                 \
        _Pragma("unroll")                                                                  \
        for (int c = 0; c < 4; ++c){                                                       \
          int idx = c * 256 + tid;                                                         \
          int kpair = idx >> 4, oq = idx & 15;                                             \
          int k = (K0) + kpair * 2;                                                        \
          float4 w0 = *(const float4*)(W + (size_t)k * OUTD + tn + oq * 4);                \
          float4 w1 = *(const float4*)(W + (size_t)(k + 1) * OUTD + tn + oq * 4);          \
          int krel = kpair * 2;                                                            \
          int gch = krel >> 3, kb = krel & 7;                                              \
          float wa0[4] = {w0.x, w0.y, w0.z, w0.w};                                         \
          float wa1[4] = {w1.x, w1.y, w1.z, w1.w};                                         \
          _Pragma("unroll")                                                                \
          for (int j = 0; j < 4; ++j){                                                     \
            int row = oq * 4 + j;                                                          \
            int ch = gch ^ (row & 15);                                                     \
            u32 val = (u32)f2bf(wa0[j]) | ((u32)f2bf(wa1[j]) << 16);                       \
            *(u32*)(BS + (buf)*8192 + row*128 + ch*8 + kb) = val;                          \
          }                                                                                \
        }                                                                                  \
      } while (0)

    STAGE_BW(0, 0);
    STAGE_A(0, 0);
    __syncthreads();

    for (int s = 0; s < 8; ++s){
      if (s < 7){ STAGE_BW(cur ^ 1, (s + 1) * 128); STAGE_A(cur ^ 1, (s + 1) * 128); }
      #pragma unroll
      for (int kk = 0; kk < 4; ++kk){
        bf16x8 af[2], bfr[2];
        #pragma unroll
        for (int m = 0; m < 2; ++m){
          int row = wm + m*16 + lr;
          int ch  = (kk*4 + kq) ^ (row & 15);
          af[m] = __builtin_bit_cast(bf16x8, *(const uint4*)(AS + cur*8192 + row*128 + ch*8));
        }
        #pragma unroll
        for (int n = 0; n < 2; ++n){
          int row = wn + n*16 + lr;
          int ch  = (kk*4 + kq) ^ (row & 15);
          bfr[n] = __builtin_bit_cast(bf16x8, *(const uint4*)(BS + cur*8192 + row*128 + ch*8));
        }
        #pragma unroll
        for (int m = 0; m < 2; ++m)
          #pragma unroll
          for (int n = 0; n < 2; ++n)
            acc[m][n] = __builtin_amdgcn_mfma_f32_16x16x32_bf16(af[m], bfr[n], acc[m][n], 0, 0, 0);
      }
      __syncthreads();
      cur ^= 1;
    }
    #undef STAGE_A
    #undef STAGE_BW

    #pragma unroll
    for (int n = 0; n < 2; ++n)
      #pragma unroll
      for (int m = 0; m < 2; ++m){
        int row = tm + wm + m*16 + kq*4;
        int col = tn + wn + n*16 + lr;
        #pragma unroll
        for (int q = 0; q < 4; ++q)
          U[(size_t)(row + q) * OUTD + col] = f2bf(acc[m][n][q]);
      }
  } else if (bid < NB_GEMM + NB_DIST){
    // ---------------- dist role: 4 (b,r) pairs per wave, same b (Q hoisted) ----------------
    const int w = tid >> 6, l = tid & 63;
    const int base = (bid - NB_GEMM) * 16 + w * 4;
    const int b = base >> 12;
    const int q0 = Q[b*DB + l],   q1 = Q[b*DB + 64 + l];
    const int a0 = Qok[b*DB + l], a1 = Qok[b*DB + 64 + l];
    #pragma unroll
    for (int i = 0; i < 4; ++i){
      int r = (base + i) & 4095;
      int f0 = refs[r*DB + l], f1 = refs[r*DB + 64 + l];
      int p0 = okpos[r*DB + l],p1 = okpos[r*DB + 64 + l];
      int m = __popc(q0 & f0) + __popc(q1 & f1);
      int o = __popc(a0 & p0) + __popc(a1 & p1);
      int v = m | (o << 16);
      #pragma unroll
      for (int off = 32; off; off >>= 1) v += __shfl_down(v, off);
      if (l == 0) distsT[r * 8 + b] = (float)(v & 0xffff) / (float)(v >> 16);
    }
  } else {
    // ---------------- bounds role ----------------
    int n = (bid - NB_GEMM - NB_DIST) * 256 + tid;   // n in [0,1024)
    int lo = 0, hi = S_EDGE;
    #pragma unroll 1
    while (lo < hi){ int mid = (lo + hi) >> 1; if (segments[mid] < n) lo = mid + 1; else hi = mid; }
    segstart[n] = lo;
    if (n == 0) segstart[NSEG] = S_EDGE;
  }
}

// Fused per-segment: stats (wave0) + score->LDS + scatter-FMA (bf16 U).  [R9 verbatim]
__global__ __launch_bounds__(256) void k_scat(const float* __restrict__ distsT,
                                              const int* __restrict__ ref2seg,
                                              const int* __restrict__ segstart,
                                              const unsigned short* __restrict__ U,
                                              const float* __restrict__ bo,
                                              float* __restrict__ out){
  __shared__ float mbs[8], ibs[8];
  __shared__ float scl[TILE_E * 8];
  __shared__ int   rix[TILE_E];
  const int n = blockIdx.x;
  const int t = threadIdx.x;

  const int start = segstart[n], end = segstart[n + 1];

  const float b0c = bo[2*t], b1c = bo[2*t + 1];
  float* op = out + (size_t)n * OUTD + 2*t;

  if (start >= end){
    #pragma unroll
    for (int j = 0; j < 8; ++j){
      op[(size_t)j * NSEG * OUTD]     = b0c;
      op[(size_t)j * NSEG * OUTD + 1] = b1c;
    }
    return;
  }

  if (t < 64){
    const int sb = t >> 3, es = t & 7;
    float m = -1e30f, s = 0.f;
    for (int e = start + es; e < end; e += 8){
      float d = distsT[ref2seg[e] * 8 + sb];
      float mn = fmaxf(m, d);
      s = s * __expf(m - mn) + __expf(d - mn);
      m = mn;
    }
    #pragma unroll
    for (int msk = 1; msk < 8; msk <<= 1){
      float mo = __shfl_xor(m, msk), so = __shfl_xor(s, msk);
      float mn = fmaxf(m, mo);
      s = s * __expf(m - mn) + so * __expf(mo - mn);
      m = mn;
    }
    if (es == 0){ mbs[sb] = m; ibs[sb] = 1.0f / s; }
  }
  __syncthreads();

  float acc[8][2];
  #pragma unroll
  for (int j = 0; j < 8; ++j){ acc[j][0] = 0.f; acc[j][1] = 0.f; }

  for (int e0 = start; e0 < end; e0 += TILE_E){
    const int cnt = min(TILE_E, end - e0);
    for (int i = t; i < cnt * 8; i += 256){
      int e = e0 + (i >> 3), b = i & 7;
      int r = ref2seg[e];
      if (b == 0) rix[i >> 3] = r;
      scl[i] = __expf(distsT[r*8 + b] - mbs[b]) * ibs[b];
    }
    __syncthreads();

    #pragma unroll 4
    for (int e = 0; e < cnt; ++e){
      int r = rix[e];
      float4 s0 = *(const float4*)(scl + e*8);
      float4 s1 = *(const float4*)(scl + e*8 + 4);
      u32 uu = *(const u32*)(U + ((size_t)r << 9) + 2*t);
      float ux = __builtin_bit_cast(float, uu << 16);
      float uy = __builtin_bit_cast(float, uu & 0xffff0000u);
      float ss[8] = {s0.x, s0.y, s0.z, s0.w, s1.x, s1.y, s1.z, s1.w};
      #pragma unroll
      for (int j = 0; j < 8; ++j){
        acc[j][0] += ss[j] * ux;
        acc[j][1] += ss[j] * uy;
      }
    }
    __syncthreads();
  }

  #pragma unroll
  for (int j = 0; j < 8; ++j){
    op[(size_t)j * NSEG * OUTD]     = acc[j][0] + b0c;
    op[(size_t)j * NSEG * OUTD + 1] = acc[j][1] + b1c;
  }
}

extern "C" void kernel_launch(void* const* d_in, const int* in_sizes, int n_in,
                              void* d_out, int out_size, void* d_ws, size_t ws_size,
                              hipStream_t stream) {
  const int*   Q        = (const int*)d_in[0];
  const int*   Qok      = (const int*)d_in[1];
  const int*   refs     = (const int*)d_in[2];
  const int*   okpos    = (const int*)d_in[3];
  const int*   ref2seg  = (const int*)d_in[4];
  const int*   segments = (const int*)d_in[5];
  const float* W        = (const float*)d_in[7];
  const float* bo       = (const float*)d_in[8];
  float* out = (float*)d_out;

  char* ws = (char*)d_ws;
  float*          distsT   = (float*)(ws + (1u<<20));                    // 128 KB
  int*            segstart = (int*)(ws + (1u<<20) + (160u<<10));         // ~4 KB
  unsigned short* U        = (unsigned short*)(ws + (11u<<20));          // [11M, 15M) bf16

  k_front<<<NB_GEMM + NB_DIST + NB_BOUNDS, 256, 0, stream>>>(W, refs, Q, Qok, okpos,
                                                             distsT, segments, segstart, U);
  k_scat <<<NSEG, 256, 0, stream>>>(distsT, ref2seg, segstart, U, bo, out);
}

// Round 11
// 48.184 us; speedup vs baseline: 1.0123x; 1.0123x over previous
//
#include <hip/hip_runtime.h>

#define B_Q   8
#define DB    128
#define R_REF 4096
#define S_EDGE 32768
#define NSEG  1024
#define DBITS 1024
#define OUTD  512

#define NB_GEMM 512
#define NB_DIST 2048
#define NB_BOUNDS 4
#define TILE_E 256

typedef __bf16 bf16_t;
typedef bf16_t bf16x8 __attribute__((ext_vector_type(8)));
typedef float  f32x4  __attribute__((ext_vector_type(4)));
typedef unsigned int u32;

__device__ inline unsigned short f2bf(float f){
  unsigned int u = __builtin_bit_cast(unsigned int, f);
  u = (u + 0x7fffu + ((u >> 16) & 1u)) >> 16;
  return (unsigned short)u;
}

__device__ __forceinline__ void gl_lds16(const unsigned short* g, unsigned short* l){
  __builtin_amdgcn_global_load_lds((const __attribute__((address_space(1))) u32*)g,
                                   (__attribute__((address_space(3))) u32*)l, 16, 0, 0);
}

// W (DBITS x OUTD f32) -> WT (OUTD x DBITS bf16), LDS-tiled transpose. 128 blocks.
__global__ __launch_bounds__(256) void k_wconv(const float* __restrict__ W,
                                               unsigned short* __restrict__ WT){
  __shared__ float tile[64][65];
  const int k0 = (blockIdx.x & 15) * 64, o0 = (blockIdx.x >> 4) * 64;
  const int tr = threadIdx.x >> 6, tc = threadIdx.x & 63;
  #pragma unroll
  for (int i = 0; i < 16; ++i)
    tile[tr + i*4][tc] = W[(size_t)(k0 + tr + i*4) * OUTD + o0 + tc];
  __syncthreads();
  #pragma unroll
  for (int i = 0; i < 16; ++i)
    WT[(size_t)(o0 + tr + i*4) * DBITS + k0 + tc] = f2bf(tile[tc][tr + i*4]);
}

// Fused mid: [0,512) GEMM (R9 structure) | [512,2560) dists | [2560,2564) bounds
__global__ __launch_bounds__(256) void k_mid(const int* __restrict__ refs,
                                             const unsigned short* __restrict__ WT,
                                             unsigned short* __restrict__ U,
                                             const int* __restrict__ Q,
                                             const int* __restrict__ Qok,
                                             const int* __restrict__ okpos,
                                             float* __restrict__ distsT,
                                             const int* __restrict__ segments,
                                             int* __restrict__ segstart){
  __shared__ unsigned short AS[2 * 8192];   // 32 KB
  __shared__ unsigned short BS[2 * 8192];   // 32 KB
  const int bid = blockIdx.x;
  const int tid = threadIdx.x;

  if (bid < NB_GEMM){
    // ---- GEMM role: U[4096][512] bf16 = unpackbits(refs) @ W. 64^2, BK=128, dbuf ----
    const int tn = (bid & 7) * 64, tm = (bid >> 3) * 64;   // XCD-affine columns
    const int w = tid >> 6, l = tid & 63;
    const int wm = (w & 1) * 32, wn = (w >> 1) * 32;
    const int lr = l & 15, kq = l >> 4;

    f32x4 acc[2][2] = {};
    int cur = 0;

    #define STAGE_B(buf, K0)                                                               \
      do {                                                                                 \
        _Pragma("unroll")                                                                  \
        for (int c = 0; c < 4; ++c){                                                       \
          int idx = c * 256 + tid;                                                         \
          int row = idx >> 4, ch = idx & 15;                                               \
          int gch = ch ^ (row & 15);                                                       \
          gl_lds16(WT + (size_t)(tn + row) * DBITS + (K0) + gch*8,                         \
                   BS + (buf)*8192 + row*128 + ch*8);                                      \
        }                                                                                  \
      } while (0)

    #define STAGE_A(buf, K0)                                                               \
      do {                                                                                 \
        int row = tid >> 2, j0 = (tid & 3) * 4;                                            \
        int4 rv = *(const int4*)(refs + (size_t)(tm + row) * DB + (K0)/8 + j0);            \
        const int rx = row & 15;                                                           \
        int vv[4] = {rv.x, rv.y, rv.z, rv.w};                                              \
        _Pragma("unroll")                                                                  \
        for (int j = 0; j < 4; ++j){                                                       \
          u32 v = (u32)vv[j];                                                              \
          uint4 o;                                                                         \
          u32* wp = (u32*)&o;                                                              \
          _Pragma("unroll")                                                                \
          for (int i2 = 0; i2 < 4; ++i2){                                                  \
            u32 b0 = (v >> (7 - 2*i2)) & 1u;                                               \
            u32 b1 = (v >> (6 - 2*i2)) & 1u;                                               \
            wp[i2] = b0 * 0x3F80u | ((b1 * 0x3F80u) << 16);                                \
          }                                                                                \
          int lch = (j0 + j) ^ rx;                                                         \
          *(uint4*)(AS + (buf)*8192 + row*128 + lch*8) = o;                                \
        }                                                                                  \
      } while (0)

    STAGE_B(0, 0);
    STAGE_A(0, 0);
    __syncthreads();

    for (int s = 0; s < 8; ++s){
      if (s < 7){ STAGE_B(cur ^ 1, (s + 1) * 128); STAGE_A(cur ^ 1, (s + 1) * 128); }
      #pragma unroll
      for (int kk = 0; kk < 4; ++kk){
        bf16x8 af[2], bfr[2];
        #pragma unroll
        for (int m = 0; m < 2; ++m){
          int row = wm + m*16 + lr;
          int ch  = (kk*4 + kq) ^ (row & 15);
          af[m] = __builtin_bit_cast(bf16x8, *(const uint4*)(AS + cur*8192 + row*128 + ch*8));
        }
        #pragma unroll
        for (int n = 0; n < 2; ++n){
          int row = wn + n*16 + lr;
          int ch  = (kk*4 + kq) ^ (row & 15);
          bfr[n] = __builtin_bit_cast(bf16x8, *(const uint4*)(BS + cur*8192 + row*128 + ch*8));
        }
        #pragma unroll
        for (int m = 0; m < 2; ++m)
          #pragma unroll
          for (int n = 0; n < 2; ++n)
            acc[m][n] = __builtin_amdgcn_mfma_f32_16x16x32_bf16(af[m], bfr[n], acc[m][n], 0, 0, 0);
      }
      __syncthreads();
      cur ^= 1;
    }
    #undef STAGE_A
    #undef STAGE_B

    #pragma unroll
    for (int n = 0; n < 2; ++n)
      #pragma unroll
      for (int m = 0; m < 2; ++m){
        int row = tm + wm + m*16 + kq*4;
        int col = tn + wn + n*16 + lr;
        #pragma unroll
        for (int q = 0; q < 4; ++q)
          U[(size_t)(row + q) * OUTD + col] = f2bf(acc[m][n][q]);
      }
  } else if (bid < NB_GEMM + NB_DIST){
    // ---- dist role: 4 (b,r) pairs per wave, same b (Q hoisted) ----
    const int w = tid >> 6, l = tid & 63;
    const int base = (bid - NB_GEMM) * 16 + w * 4;
    const int b = base >> 12;
    const int q0 = Q[b*DB + l],   q1 = Q[b*DB + 64 + l];
    const int a0 = Qok[b*DB + l], a1 = Qok[b*DB + 64 + l];
    #pragma unroll
    for (int i = 0; i < 4; ++i){
      int r = (base + i) & 4095;
      int f0 = refs[r*DB + l], f1 = refs[r*DB + 64 + l];
      int p0 = okpos[r*DB + l],p1 = okpos[r*DB + 64 + l];
      int m = __popc(q0 & f0) + __popc(q1 & f1);
      int o = __popc(a0 & p0) + __popc(a1 & p1);
      int v = m | (o << 16);
      #pragma unroll
      for (int off = 32; off; off >>= 1) v += __shfl_down(v, off);
      if (l == 0) distsT[r * 8 + b] = (float)(v & 0xffff) / (float)(v >> 16);
    }
  } else {
    // ---- bounds role ----
    int n = (bid - NB_GEMM - NB_DIST) * 256 + tid;   // n in [0,1024)
    int lo = 0, hi = S_EDGE;
    #pragma unroll 1
    while (lo < hi){ int mid = (lo + hi) >> 1; if (segments[mid] < n) lo = mid + 1; else hi = mid; }
    segstart[n] = lo;
    if (n == 0) segstart[NSEG] = S_EDGE;
  }
}

// Fused per-segment: stats (wave0) + score->LDS + scatter-FMA (bf16 U).  [R9 verbatim]
__global__ __launch_bounds__(256) void k_scat(const float* __restrict__ distsT,
                                              const int* __restrict__ ref2seg,
                                              const int* __restrict__ segstart,
                                              const unsigned short* __restrict__ U,
                                              const float* __restrict__ bo,
                                              float* __restrict__ out){
  __shared__ float mbs[8], ibs[8];
  __shared__ float scl[TILE_E * 8];
  __shared__ int   rix[TILE_E];
  const int n = blockIdx.x;
  const int t = threadIdx.x;

  const int start = segstart[n], end = segstart[n + 1];

  const float b0c = bo[2*t], b1c = bo[2*t + 1];
  float* op = out + (size_t)n * OUTD + 2*t;

  if (start >= end){
    #pragma unroll
    for (int j = 0; j < 8; ++j){
      op[(size_t)j * NSEG * OUTD]     = b0c;
      op[(size_t)j * NSEG * OUTD + 1] = b1c;
    }
    return;
  }

  if (t < 64){
    const int sb = t >> 3, es = t & 7;
    float m = -1e30f, s = 0.f;
    for (int e = start + es; e < end; e += 8){
      float d = distsT[ref2seg[e] * 8 + sb];
      float mn = fmaxf(m, d);
      s = s * __expf(m - mn) + __expf(d - mn);
      m = mn;
    }
    #pragma unroll
    for (int msk = 1; msk < 8; msk <<= 1){
      float mo = __shfl_xor(m, msk), so = __shfl_xor(s, msk);
      float mn = fmaxf(m, mo);
      s = s * __expf(m - mn) + so * __expf(mo - mn);
      m = mn;
    }
    if (es == 0){ mbs[sb] = m; ibs[sb] = 1.0f / s; }
  }
  __syncthreads();

  float acc[8][2];
  #pragma unroll
  for (int j = 0; j < 8; ++j){ acc[j][0] = 0.f; acc[j][1] = 0.f; }

  for (int e0 = start; e0 < end; e0 += TILE_E){
    const int cnt = min(TILE_E, end - e0);
    for (int i = t; i < cnt * 8; i += 256){
      int e = e0 + (i >> 3), b = i & 7;
      int r = ref2seg[e];
      if (b == 0) rix[i >> 3] = r;
      scl[i] = __expf(distsT[r*8 + b] - mbs[b]) * ibs[b];
    }
    __syncthreads();

    #pragma unroll 4
    for (int e = 0; e < cnt; ++e){
      int r = rix[e];
      float4 s0 = *(const float4*)(scl + e*8);
      float4 s1 = *(const float4*)(scl + e*8 + 4);
      u32 uu = *(const u32*)(U + ((size_t)r << 9) + 2*t);
      float ux = __builtin_bit_cast(float, uu << 16);
      float uy = __builtin_bit_cast(float, uu & 0xffff0000u);
      float ss[8] = {s0.x, s0.y, s0.z, s0.w, s1.x, s1.y, s1.z, s1.w};
      #pragma unroll
      for (int j = 0; j < 8; ++j){
        acc[j][0] += ss[j] * ux;
        acc[j][1] += ss[j] * uy;
      }
    }
    __syncthreads();
  }

  #pragma unroll
  for (int j = 0; j < 8; ++j){
    op[(size_t)j * NSEG * OUTD]     = acc[j][0] + b0c;
    op[(size_t)j * NSEG * OUTD + 1] = acc[j][1] + b1c;
  }
}

extern "C" void kernel_launch(void* const* d_in, const int* in_sizes, int n_in,
                              void* d_out, int out_size, void* d_ws, size_t ws_size,
                              hipStream_t stream) {
  const int*   Q        = (const int*)d_in[0];
  const int*   Qok      = (const int*)d_in[1];
  const int*   refs     = (const int*)d_in[2];
  const int*   okpos    = (const int*)d_in[3];
  const int*   ref2seg  = (const int*)d_in[4];
  const int*   segments = (const int*)d_in[5];
  const float* W        = (const float*)d_in[7];
  const float* bo       = (const float*)d_in[8];
  float* out = (float*)d_out;

  char* ws = (char*)d_ws;
  unsigned short* WT       = (unsigned short*)ws;                        // [0, 1M)
  float*          distsT   = (float*)(ws + (1u<<20));                    // 128 KB
  int*            segstart = (int*)(ws + (1u<<20) + (160u<<10));         // ~4 KB
  unsigned short* U        = (unsigned short*)(ws + (11u<<20));          // [11M, 15M) bf16

  k_wconv<<<128, 256, 0, stream>>>(W, WT);
  k_mid  <<<NB_GEMM + NB_DIST + NB_BOUNDS, 256, 0, stream>>>(refs, WT, U, Q, Qok, okpos,
                                                             distsT, segments, segstart);
  k_scat <<<NSEG, 256, 0, stream>>>(distsT, ref2seg, segstart, U, bo, out);
}

// Round 12
// 42.462 us; speedup vs baseline: 1.1488x; 1.1348x over previous
//
#include <hip/hip_runtime.h>

#define B_Q   8
#define DB    128
#define R_REF 4096
#define S_EDGE 32768
#define NSEG  1024
#define DBITS 1024
#define OUTD  512

#define NB_WCONV 128
#define NB_DIST 2048
#define NB_BOUNDS 4
#define TILE_E 256

typedef __bf16 bf16_t;
typedef bf16_t bf16x8 __attribute__((ext_vector_type(8)));
typedef float  f32x4  __attribute__((ext_vector_type(4)));
typedef unsigned int u32;

__device__ inline unsigned short f2bf(float f){
  unsigned int u = __builtin_bit_cast(unsigned int, f);
  u = (u + 0x7fffu + ((u >> 16) & 1u)) >> 16;
  return (unsigned short)u;
}

__device__ __forceinline__ void gl_lds16(const unsigned short* g, unsigned short* l){
  __builtin_amdgcn_global_load_lds((const __attribute__((address_space(1))) u32*)g,
                                   (__attribute__((address_space(3))) u32*)l, 16, 0, 0);
}

// Fused prep: [0,128) W transpose | [128,2176) dists (4 pairs/wave) | [2176,2180) bounds
__global__ __launch_bounds__(256) void k_prep(const float* __restrict__ W,
                                              unsigned short* __restrict__ WT,
                                              const int* __restrict__ refs,
                                              const int* __restrict__ Q,
                                              const int* __restrict__ Qok,
                                              const int* __restrict__ okpos,
                                              float* __restrict__ distsT,
                                              const int* __restrict__ segments,
                                              int* __restrict__ segstart){
  __shared__ float tile[64][65];
  const int bid = blockIdx.x;
  const int tid = threadIdx.x;

  if (bid < NB_WCONV){
    const int k0 = (bid & 15) * 64, o0 = (bid >> 4) * 64;
    const int tr = tid >> 6, tc = tid & 63;
    #pragma unroll
    for (int i = 0; i < 16; ++i)
      tile[tr + i*4][tc] = W[(size_t)(k0 + tr + i*4) * OUTD + o0 + tc];
    __syncthreads();
    #pragma unroll
    for (int i = 0; i < 16; ++i)
      WT[(size_t)(o0 + tr + i*4) * DBITS + k0 + tc] = f2bf(tile[tc][tr + i*4]);
  } else if (bid < NB_WCONV + NB_DIST){
    // dist: 4 (b,r) pairs per wave, same b (Q/Qok hoisted); 8 loads in flight
    const int w = tid >> 6, l = tid & 63;
    const int base = (bid - NB_WCONV) * 16 + w * 4;
    const int b = base >> 12;
    const int q0 = Q[b*DB + l],   q1 = Q[b*DB + 64 + l];
    const int a0 = Qok[b*DB + l], a1 = Qok[b*DB + 64 + l];
    #pragma unroll
    for (int i = 0; i < 4; ++i){
      int r = (base + i) & 4095;
      int f0 = refs[r*DB + l], f1 = refs[r*DB + 64 + l];
      int p0 = okpos[r*DB + l],p1 = okpos[r*DB + 64 + l];
      int m = __popc(q0 & f0) + __popc(q1 & f1);
      int o = __popc(a0 & p0) + __popc(a1 & p1);
      int v = m | (o << 16);
      #pragma unroll
      for (int off = 32; off; off >>= 1) v += __shfl_down(v, off);
      if (l == 0) distsT[r * 8 + b] = (float)(v & 0xffff) / (float)(v >> 16);
    }
  } else {
    int n = (bid - NB_WCONV - NB_DIST) * 256 + tid;   // n in [0,1024)
    int lo = 0, hi = S_EDGE;
    #pragma unroll 1
    while (lo < hi){ int mid = (lo + hi) >> 1; if (segments[mid] < n) lo = mid + 1; else hi = mid; }
    segstart[n] = lo;
    if (n == 0) segstart[NSEG] = S_EDGE;
  }
}

// U[4096][512] bf16 = unpackbits(refs) @ W. 64^2, BK=128, dbuf, XCD-affine 1D grid.
__global__ __launch_bounds__(256) void k_ugemm(const int* __restrict__ refs,
                                               const unsigned short* __restrict__ WT,
                                               unsigned short* __restrict__ U){
  __shared__ unsigned short AS[2 * 8192];   // 32 KB
  __shared__ unsigned short BS[2 * 8192];   // 32 KB
  const int tid = threadIdx.x;
  const int bid = blockIdx.x;
  const int tn = (bid & 7) * 64, tm = (bid >> 3) * 64;   // XCD owns one N column-group
  const int w = tid >> 6, l = tid & 63;
  const int wm = (w & 1) * 32, wn = (w >> 1) * 32;
  const int lr = l & 15, kq = l >> 4;

  f32x4 acc[2][2] = {};
  int cur = 0;

  #define STAGE_B(buf, K0)                                                                 \
    do {                                                                                   \
      _Pragma("unroll")                                                                    \
      for (int c = 0; c < 4; ++c){                                                         \
        int idx = c * 256 + tid;                                                           \
        int row = idx >> 4, ch = idx & 15;                                                 \
        int gch = ch ^ (row & 15);                                                         \
        gl_lds16(WT + (size_t)(tn + row) * DBITS + (K0) + gch*8,                           \
                 BS + (buf)*8192 + row*128 + ch*8);                                        \
      }                                                                                    \
    } while (0)

  #define STAGE_A(buf, K0)                                                                 \
    do {                                                                                   \
      int row = tid >> 2, j0 = (tid & 3) * 4;                                              \
      int4 rv = *(const int4*)(refs + (size_t)(tm + row) * DB + (K0)/8 + j0);              \
      const int rx = row & 15;                                                             \
      int vv[4] = {rv.x, rv.y, rv.z, rv.w};                                                \
      _Pragma("unroll")                                                                    \
      for (int j = 0; j < 4; ++j){                                                         \
        u32 v = (u32)vv[j];                                                                \
        uint4 o;                                                                           \
        u32* wp = (u32*)&o;                                                                \
        _Pragma("unroll")                                                                  \
        for (int i2 = 0; i2 < 4; ++i2){                                                    \
          u32 b0 = (v >> (7 - 2*i2)) & 1u;                                                 \
          u32 b1 = (v >> (6 - 2*i2)) & 1u;                                                 \
          wp[i2] = b0 * 0x3F80u | ((b1 * 0x3F80u) << 16);                                  \
        }                                                                                  \
        int lch = (j0 + j) ^ rx;                                                           \
        *(uint4*)(AS + (buf)*8192 + row*128 + lch*8) = o;                                  \
      }                                                                                    \
    } while (0)

  STAGE_B(0, 0);
  STAGE_A(0, 0);
  __syncthreads();

  for (int s = 0; s < 8; ++s){
    if (s < 7){ STAGE_B(cur ^ 1, (s + 1) * 128); STAGE_A(cur ^ 1, (s + 1) * 128); }
    #pragma unroll
    for (int kk = 0; kk < 4; ++kk){
      bf16x8 af[2], bfr[2];
      #pragma unroll
      for (int m = 0; m < 2; ++m){
        int row = wm + m*16 + lr;
        int ch  = (kk*4 + kq) ^ (row & 15);
        af[m] = __builtin_bit_cast(bf16x8, *(const uint4*)(AS + cur*8192 + row*128 + ch*8));
      }
      #pragma unroll
      for (int n = 0; n < 2; ++n){
        int row = wn + n*16 + lr;
        int ch  = (kk*4 + kq) ^ (row & 15);
        bfr[n] = __builtin_bit_cast(bf16x8, *(const uint4*)(BS + cur*8192 + row*128 + ch*8));
      }
      #pragma unroll
      for (int m = 0; m < 2; ++m)
        #pragma unroll
        for (int n = 0; n < 2; ++n)
          acc[m][n] = __builtin_amdgcn_mfma_f32_16x16x32_bf16(af[m], bfr[n], acc[m][n], 0, 0, 0);
    }
    __syncthreads();
    cur ^= 1;
  }
  #undef STAGE_A
  #undef STAGE_B

  #pragma unroll
  for (int n = 0; n < 2; ++n)
    #pragma unroll
    for (int m = 0; m < 2; ++m){
      int row = tm + wm + m*16 + kq*4;
      int col = tn + wn + n*16 + lr;
      #pragma unroll
      for (int q = 0; q < 4; ++q)
        U[(size_t)(row + q) * OUTD + col] = f2bf(acc[m][n][q]);
    }
}

// Fused per-segment: stats (wave0) + score->LDS + scatter-FMA (bf16 U).  [R9 verbatim]
__global__ __launch_bounds__(256) void k_scat(const float* __restrict__ distsT,
                                              const int* __restrict__ ref2seg,
                                              const int* __restrict__ segstart,
                                              const unsigned short* __restrict__ U,
                                              const float* __restrict__ bo,
                                              float* __restrict__ out){
  __shared__ float mbs[8], ibs[8];
  __shared__ float scl[TILE_E * 8];
  __shared__ int   rix[TILE_E];
  const int n = blockIdx.x;
  const int t = threadIdx.x;

  const int start = segstart[n], end = segstart[n + 1];

  const float b0c = bo[2*t], b1c = bo[2*t + 1];
  float* op = out + (size_t)n * OUTD + 2*t;

  if (start >= end){
    #pragma unroll
    for (int j = 0; j < 8; ++j){
      op[(size_t)j * NSEG * OUTD]     = b0c;
      op[(size_t)j * NSEG * OUTD + 1] = b1c;
    }
    return;
  }

  if (t < 64){
    const int sb = t >> 3, es = t & 7;
    float m = -1e30f, s = 0.f;
    for (int e = start + es; e < end; e += 8){
      float d = distsT[ref2seg[e] * 8 + sb];
      float mn = fmaxf(m, d);
      s = s * __expf(m - mn) + __expf(d - mn);
      m = mn;
    }
    #pragma unroll
    for (int msk = 1; msk < 8; msk <<= 1){
      float mo = __shfl_xor(m, msk), so = __shfl_xor(s, msk);
      float mn = fmaxf(m, mo);
      s = s * __expf(m - mn) + so * __expf(mo - mn);
      m = mn;
    }
    if (es == 0){ mbs[sb] = m; ibs[sb] = 1.0f / s; }
  }
  __syncthreads();

  float acc[8][2];
  #pragma unroll
  for (int j = 0; j < 8; ++j){ acc[j][0] = 0.f; acc[j][1] = 0.f; }

  for (int e0 = start; e0 < end; e0 += TILE_E){
    const int cnt = min(TILE_E, end - e0);
    for (int i = t; i < cnt * 8; i += 256){
      int e = e0 + (i >> 3), b = i & 7;
      int r = ref2seg[e];
      if (b == 0) rix[i >> 3] = r;
      scl[i] = __expf(distsT[r*8 + b] - mbs[b]) * ibs[b];
    }
    __syncthreads();

    #pragma unroll 4
    for (int e = 0; e < cnt; ++e){
      int r = rix[e];
      float4 s0 = *(const float4*)(scl + e*8);
      float4 s1 = *(const float4*)(scl + e*8 + 4);
      u32 uu = *(const u32*)(U + ((size_t)r << 9) + 2*t);
      float ux = __builtin_bit_cast(float, uu << 16);
      float uy = __builtin_bit_cast(float, uu & 0xffff0000u);
      float ss[8] = {s0.x, s0.y, s0.z, s0.w, s1.x, s1.y, s1.z, s1.w};
      #pragma unroll
      for (int j = 0; j < 8; ++j){
        acc[j][0] += ss[j] * ux;
        acc[j][1] += ss[j] * uy;
      }
    }
    __syncthreads();
  }

  #pragma unroll
  for (int j = 0; j < 8; ++j){
    op[(size_t)j * NSEG * OUTD]     = acc[j][0] + b0c;
    op[(size_t)j * NSEG * OUTD + 1] = acc[j][1] + b1c;
  }
}

extern "C" void kernel_launch(void* const* d_in, const int* in_sizes, int n_in,
                              void* d_out, int out_size, void* d_ws, size_t ws_size,
                              hipStream_t stream) {
  const int*   Q        = (const int*)d_in[0];
  const int*   Qok      = (const int*)d_in[1];
  const int*   refs     = (const int*)d_in[2];
  const int*   okpos    = (const int*)d_in[3];
  const int*   ref2seg  = (const int*)d_in[4];
  const int*   segments = (const int*)d_in[5];
  const float* W        = (const float*)d_in[7];
  const float* bo       = (const float*)d_in[8];
  float* out = (float*)d_out;

  char* ws = (char*)d_ws;
  unsigned short* WT       = (unsigned short*)ws;                        // [0, 1M)
  float*          distsT   = (float*)(ws + (1u<<20));                    // 128 KB
  int*            segstart = (int*)(ws + (1u<<20) + (160u<<10));         // ~4 KB
  unsigned short* U        = (unsigned short*)(ws + (11u<<20));          // [11M, 15M) bf16

  k_prep <<<NB_WCONV + NB_DIST + NB_BOUNDS, 256, 0, stream>>>(W, WT, refs, Q, Qok, okpos,
                                                              distsT, segments, segstart);
  k_ugemm<<<R_REF/64 * (OUTD/64), 256, 0, stream>>>(refs, WT, U);
  k_scat <<<NSEG, 256, 0, stream>>>(distsT, ref2seg, segstart, U, bo, out);
}